// Round 9
// baseline (3162.006 us; speedup 1.0000x reference)
//
#include <hip/hip_runtime.h>

typedef _Float16 f16;
typedef __attribute__((ext_vector_type(4))) _Float16 f16x4;
typedef __attribute__((ext_vector_type(8))) _Float16 f16x8;
typedef __attribute__((ext_vector_type(4))) float f32x4;

__device__ __forceinline__ float tanh_fast(float x) {
  float e = __expf(2.0f * x);
  return 1.0f - 2.0f * __builtin_amdgcn_rcpf(e + 1.0f);
}

// raw LDS-only workgroup sync: no vmcnt drain (keeps global prefetches alive)
__device__ __forceinline__ void wg_sync_lds() {
  asm volatile("s_waitcnt lgkmcnt(0)" ::: "memory");
  __builtin_amdgcn_sched_barrier(0);
  __builtin_amdgcn_s_barrier();
  __builtin_amdgcn_sched_barrier(0);
}

#if defined(__has_builtin)
#if __has_builtin(__builtin_amdgcn_global_load_lds)
#define USE_GLL 1
#endif
#endif
#ifndef USE_GLL
#define USE_GLL 0
#endif

__device__ __forceinline__ void gll16(const void* g, void* l) {
#if USE_GLL
  __builtin_amdgcn_global_load_lds(
      (const __attribute__((address_space(1))) unsigned int*)g,
      (__attribute__((address_space(3))) unsigned int*)l, 16, 0, 0);
#endif
}

// ---------------- fp32 -> fp16 convert (grid-stride, float4) ----------------
__global__ void k_cvt_f16(const float* __restrict__ in, f16* __restrict__ out, int n4) {
  int i = blockIdx.x * blockDim.x + threadIdx.x;
  int stride = gridDim.x * blockDim.x;
  for (; i < n4; i += stride) {
    float4 v = reinterpret_cast<const float4*>(in)[i];
    f16x4 o;
    o[0] = (f16)v.x; o[1] = (f16)v.y; o[2] = (f16)v.z; o[3] = (f16)v.w;
    *reinterpret_cast<f16x4*>(out + (size_t)i * 4) = o;
  }
}

// ------------- 512x512 transpose + convert: out[n][k] = f16(in[k][n]) -------
__global__ __launch_bounds__(256) void k_transpose_cvt(const float* __restrict__ in,
                                                       f16* __restrict__ out) {
  __shared__ float tile[32][33];
  int bx = blockIdx.x & 15, by = blockIdx.x >> 4;
  int tx = threadIdx.x & 31, ty = threadIdx.x >> 5;
#pragma unroll
  for (int i = 0; i < 4; ++i)
    tile[ty + i * 8][tx] = in[(size_t)(by * 32 + ty + i * 8) * 512 + bx * 32 + tx];
  __syncthreads();
#pragma unroll
  for (int i = 0; i < 4; ++i)
    out[(size_t)(bx * 32 + ty + i * 8) * 512 + by * 32 + tx] = (f16)tile[tx][ty + i * 8];
}

// --------- W_hh frag-pack: Wf[cb][kt][q][c][e] = f16(W_hh[kt*32+q*8+e][cb*16+c])
__global__ __launch_bounds__(256) void k_packW(const float* __restrict__ Whh,
                                               f16* __restrict__ Wf) {
  int id = blockIdx.x * 256 + threadIdx.x;
  int c = id & 15, q = (id >> 4) & 3, kt = (id >> 6) & 15, cb = id >> 10;
  f16x8 blk;
#pragma unroll
  for (int e = 0; e < 8; ++e)
    blk[e] = (f16)Whh[(size_t)(kt * 32 + q * 8 + e) * 512 + cb * 16 + c];
  reinterpret_cast<f16x8*>(Wf)[id] = blk;
}

// ---------------- fp16 MFMA GEMM: C[M][N] = A[M][K] * Bt[N][K]^T + bias -----
// OUT: 0 = f32 linear, 2 = f16 packed-xw (scan-ready layout, ts-major blocks)
#define BM 128
#define BN 128
#define BK 32

template <int OUT>
__global__ __launch_bounds__(256, 2) void k_gemm(const f16* __restrict__ A,
                                                 const f16* __restrict__ Bt,
                                                 const float* __restrict__ bias,
                                                 void* __restrict__ Cout,
                                                 int M, int N, int K) {
  __shared__ __align__(16) f16 As[2][BM][BK];
  __shared__ __align__(16) f16 Bs[2][BN][BK];

  const int tid = threadIdx.x;
  const int w = tid >> 6;
  const int l = tid & 63;
  const int nbn = N / BN;
  const int bm0 = (int)(blockIdx.x / nbn) * BM;
  const int bn0 = (int)(blockIdx.x % nbn) * BN;
  const int wm = w >> 1, wn = w & 1;

  auto stage = [&](int buf, int kt) {
#pragma unroll
    for (int c = 0; c < 2; ++c) {
      const int row = c * 64 + w * 16 + (l >> 2);
      const int ke = kt + (l & 3) * 8;
#if USE_GLL
      gll16(A + (size_t)(bm0 + row) * K + ke, &As[buf][c * 64 + w * 16][0]);
      gll16(Bt + (size_t)(bn0 + row) * K + ke, &Bs[buf][c * 64 + w * 16][0]);
#else
      *(f16x8*)&As[buf][row][(l & 3) * 8] = *(const f16x8*)(A + (size_t)(bm0 + row) * K + ke);
      *(f16x8*)&Bs[buf][row][(l & 3) * 8] = *(const f16x8*)(Bt + (size_t)(bn0 + row) * K + ke);
#endif
    }
  };

  f32x4 acc[4][4] = {};
  const int nkt = K / BK;
  stage(0, 0);
  int cur = 0;
  for (int kt = 0; kt < nkt; ++kt) {
    __syncthreads();
    if (kt + 1 < nkt) stage(cur ^ 1, (kt + 1) * BK);
    f16x8 af[4], bfr[4];
#pragma unroll
    for (int m = 0; m < 4; ++m)
      af[m] = *(const f16x8*)&As[cur][wm * 64 + m * 16 + (l & 15)][(l >> 4) * 8];
#pragma unroll
    for (int n = 0; n < 4; ++n)
      bfr[n] = *(const f16x8*)&Bs[cur][wn * 64 + n * 16 + (l & 15)][(l >> 4) * 8];
#pragma unroll
    for (int m = 0; m < 4; ++m)
#pragma unroll
      for (int n = 0; n < 4; ++n)
        acc[m][n] = __builtin_amdgcn_mfma_f32_16x16x32_f16(af[m], bfr[n], acc[m][n], 0, 0, 0);
    cur ^= 1;
  }

  // Epilogue. C/D layout: col = lane&15, row = (lane>>4)*4 + j  [HW-verified]
  const int r0 = bm0 + wm * 64, c0 = bn0 + wn * 64;
#pragma unroll
  for (int n = 0; n < 4; ++n) {
    const int cc = c0 + n * 16 + (l & 15);
    const float bv = bias[cc];
#pragma unroll
    for (int m = 0; m < 4; ++m) {
      const int rr = r0 + m * 16 + ((l >> 4) << 2);
      if (OUT == 2) {
        // packed xw element (b,t,cc): idx =
        //  (((((set*256+tq)*8+ww)*4+qq)*4+jj)*16+c2)*16 + ts*4 + ii;  (GEMM j == ts)
        const int b = rr >> 10, trow = rr & 1023;
        const int set = b >> 4, qq = (b >> 2) & 3, jj = b & 3;
        const int ww = (cc >> 4) & 7, ii = cc >> 7, c2 = cc & 15;
        const int tq = trow >> 2;
        f16* po = (f16*)Cout +
                  ((((((size_t)set * 256 + tq) * 8 + ww) * 4 + qq) * 4 + jj) * 16 + c2) * 16 + ii;
#pragma unroll
        for (int j = 0; j < 4; ++j) po[j * 4] = (f16)(acc[m][n][j] + bv);
      } else {
#pragma unroll
        for (int j = 0; j < 4; ++j)
          ((float*)Cout)[(size_t)(rr + j) * N + cc] = acc[m][n][j] + bv;
      }
    }
  }
}

// ---------------- RNN scan: 4 waves/CU, 6 cb in regs + 2 cb in LDS ----------
// 4 WGs x 256 threads (4 waves, 1/SIMD, 512-VGPR class). Wave w owns cbs
// {w+4i, i=0..5} register-resident (384 VGPR) and {24+w, 28+w} from LDS
// (128 KiB). h single-buffered [16][536] f16 (stride 1072B), r6's verified
// XOR frag map. hs stored directly from the tail; h_last from h3 epilogue.
// BUGFIX r9: xv group-1 loads are ww = w+4 -> offset 4*4096 = 16384 elems
// (was +4096 = ww=w+1, which corrupted odd-i2 column blocks).
#define SCAN_T 1024

__global__ __launch_bounds__(256, 1) void k_scan_w4(
    const f16* __restrict__ xwp,   // packed xw (see k_gemm OUT==2)
    const f16* __restrict__ Wf,    // frag-packed [32][16][4][16][8]
    f16* __restrict__ hs,          // [64][1024][512] linear f16 (out)
    float* __restrict__ h_last) {  // [64][512] f32 (out)
  const int tid = threadIdx.x;
  const int w = tid >> 6, l = tid & 63;
  const int q = l >> 4, c = l & 15;
  const int set = blockIdx.x;
  const int b0 = set * 16;

  __shared__ __align__(16) f16 wlds[8 * 16 * 4 * 16 * 8];  // 128 KiB: cb 24..31
  __shared__ __align__(16) f16 h3[16 * 536];               // 16.75 KiB
  char* const h3b = (char*)h3;
  char* const wldsb = (char*)wlds;

  const f16x8* WfB = (const f16x8*)Wf;

  // register-resident W: cb w+4i, i=0..5  (384 VGPR)
  f16x8 wr[6][16];
#pragma unroll
  for (int i2 = 0; i2 < 6; ++i2)
#pragma unroll
    for (int kt = 0; kt < 16; ++kt)
      wr[i2][kt] = WfB[(((w + 4 * i2) * 16 + kt) * 4 + q) * 16 + c];

  // stage cb 24..31 into wlds (32 KiB per wave, async, linear)
#pragma unroll
  for (int k2 = 0; k2 < 32; ++k2) {
    gll16(WfB + 24 * 1024 + (w * 32 + k2) * 64 + l, wldsb + (size_t)(w * 32 + k2) * 1024);
#if !USE_GLL
    ((f16x8*)wldsb)[(w * 32 + k2) * 64 + l] = WfB[24 * 1024 + (w * 32 + k2) * 64 + l];
#endif
  }
  // zero h3 (h0 = 0)
  {
    uint4* hz = (uint4*)h3b;
    for (int i = tid; i < 1072; i += 256) hz[i] = make_uint4(0u, 0u, 0u, 0u);
  }

  // addressing (r6-verified frag map, stride 1072)
  const int afbase = c * 1072 + ((q ^ (c >> 2)) << 4);   // + kt*64
  const int wlb0 = w * 16384 + q * 256 + c * 16;          // + kt*1024 (cb 24+w)
  const int wlb1 = (4 + w) * 16384 + q * 256 + c * 16;    // + kt*1024 (cb 28+w)
  int woff8[8];
#pragma unroll
  for (int i2 = 0; i2 < 8; ++i2)
    woff8[i2] = q * 4 * 1072 + ((((w + 4 * i2) * 16 + c) ^ (q << 3)) << 1);  // + j*1072

  // hs bases per j (element ptr incl. lane col offset); col += i2*64 elems
  f16* hsb[4];
#pragma unroll
  for (int j = 0; j < 4; ++j)
    hsb[j] = hs + (size_t)(b0 + q * 4 + j) * SCAN_T * 512 + w * 16 + c;

  // packed-xw lane base; per (tq,ts,h,j): + tq*32768 + h*16384 + j*256 + ts*4
  const f16* xwbase =
      xwp + ((((size_t)set * 256 * 8 + w) * 4 + q) * 4) * 256 + c * 16;

  // prologue: xv = step-0 values  (xv[j][h][ii], h selects ww = w + 4h)
  f16x4 xv[4][2];
#pragma unroll
  for (int j = 0; j < 4; ++j) {
    xv[j][0] = __builtin_nontemporal_load((const f16x4*)(xwbase + j * 256));
    xv[j][1] = __builtin_nontemporal_load((const f16x4*)(xwbase + 16384 + j * 256));
  }

  __syncthreads();  // staging + zero complete (drains gll vmcnt too)

  for (int tq = 0; tq < 256; ++tq) {
#pragma unroll
    for (int ts = 0; ts < 4; ++ts) {
      const int t = tq * 4 + ts;

      // acc init from xw (C-in of the chains)
      f32x4 acc[8];
#pragma unroll
      for (int i2 = 0; i2 < 8; ++i2)
#pragma unroll
        for (int j = 0; j < 4; ++j)
          acc[i2][j] = (float)xv[j][i2 & 1][i2 >> 1];

      // reload xv for t+1 (in flight during MFMA+tail, consumed next step)
      {
        const int tqn = (ts == 3) ? ((tq < 255) ? tq + 1 : 255) : tq;
        const int tsn = (ts + 1) & 3;
        const f16* pb = xwbase + (size_t)tqn * 32768 + tsn * 4;
#pragma unroll
        for (int j = 0; j < 4; ++j) {
          xv[j][0] = __builtin_nontemporal_load((const f16x4*)(pb + j * 256));
          xv[j][1] = __builtin_nontemporal_load((const f16x4*)(pb + 16384 + j * 256));
        }
      }

      // MFMA: 8 chains (6 reg-W, 2 LDS-W), h from LDS
#pragma unroll
      for (int kt = 0; kt < 16; ++kt) {
        f16x8 af = *(const f16x8*)(h3b + afbase + kt * 64);
        f16x8 wl0 = *(const f16x8*)(wldsb + wlb0 + kt * 1024);
        f16x8 wl1 = *(const f16x8*)(wldsb + wlb1 + kt * 1024);
        acc[0] = __builtin_amdgcn_mfma_f32_16x16x32_f16(af, wr[0][kt], acc[0], 0, 0, 0);
        acc[1] = __builtin_amdgcn_mfma_f32_16x16x32_f16(af, wr[1][kt], acc[1], 0, 0, 0);
        acc[2] = __builtin_amdgcn_mfma_f32_16x16x32_f16(af, wr[2][kt], acc[2], 0, 0, 0);
        acc[3] = __builtin_amdgcn_mfma_f32_16x16x32_f16(af, wr[3][kt], acc[3], 0, 0, 0);
        acc[4] = __builtin_amdgcn_mfma_f32_16x16x32_f16(af, wr[4][kt], acc[4], 0, 0, 0);
        acc[5] = __builtin_amdgcn_mfma_f32_16x16x32_f16(af, wr[5][kt], acc[5], 0, 0, 0);
        acc[6] = __builtin_amdgcn_mfma_f32_16x16x32_f16(af, wl0, acc[6], 0, 0, 0);
        acc[7] = __builtin_amdgcn_mfma_f32_16x16x32_f16(af, wl1, acc[7], 0, 0, 0);
      }
      wg_sync_lds();  // B1: all h3 reads of h(t) complete

      // tail: tanh + h3 write + direct hs store
#pragma unroll
      for (int i2 = 0; i2 < 8; ++i2)
#pragma unroll
        for (int j = 0; j < 4; ++j) {
          float hv = tanh_fast(acc[i2][j]);
          *(f16*)(h3b + woff8[i2] + j * 1072) = (f16)hv;
          __builtin_nontemporal_store((f16)hv, hsb[j] + (size_t)t * 512 + i2 * 64);
        }
      wg_sync_lds();  // B2: h(t+1) visible
    }
  }

  // epilogue: h_last (f32) from h3 = h(1024)
  {
    const int m = tid >> 4, kt = tid & 15;
    float* hl = h_last + (size_t)(b0 + m) * 512 + kt * 32;
#pragma unroll
    for (int kb = 0; kb < 4; ++kb) {
      f16x8 v = *(const f16x8*)(h3b + m * 1072 + kt * 64 + (((kb ^ (m >> 2)) & 3) << 4));
      float4 lo, hi;
      lo.x = (float)v[0]; lo.y = (float)v[1]; lo.z = (float)v[2]; lo.w = (float)v[3];
      hi.x = (float)v[4]; hi.y = (float)v[5]; hi.z = (float)v[6]; hi.w = (float)v[7];
      *(float4*)(hl + kb * 8) = lo;
      *(float4*)(hl + kb * 8 + 4) = hi;
    }
  }
}

// ---------------------------------------------------------------------------
extern "C" void kernel_launch(void* const* d_in, const int* in_sizes, int n_in,
                              void* d_out, int out_size, void* d_ws, size_t ws_size,
                              hipStream_t stream) {
  const float* x    = (const float*)d_in[0];
  const float* W_xh = (const float*)d_in[1];
  const float* b_h  = (const float*)d_in[2];
  const float* W_hh = (const float*)d_in[3];
  const float* W_o  = (const float*)d_in[4];
  const float* b_o  = (const float*)d_in[5];
  float* out = (float*)d_out;  // logits [64][1024][512] ++ h_last [64][512]

  const size_t XWN = (size_t)64 * 1024 * 512;
  char* ws = (char*)d_ws;
  f16* xf   = (f16*)(ws);                       // 64 MiB (x f16 -> later hs)
  f16* xwp  = (f16*)(ws + XWN * 2);             // 64 MiB (packed xW f16)
  f16* WxhT = (f16*)(ws + XWN * 4);             // 512 KiB
  f16* WoT  = (f16*)(ws + XWN * 4 + 524288);    // 512 KiB
  f16* Wf   = (f16*)(ws + XWN * 4 + 1048576);   // 512 KiB (frag-packed W_hh)

  k_cvt_f16<<<4096, 256, 0, stream>>>(x, xf, (int)(XWN / 4));
  k_transpose_cvt<<<256, 256, 0, stream>>>(W_xh, WxhT);
  k_transpose_cvt<<<256, 256, 0, stream>>>(W_o, WoT);
  k_packW<<<128, 256, 0, stream>>>(W_hh, Wf);

  // xW = x @ W_xh + b_h, written in scan-packed (ts-major) layout
  k_gemm<2><<<2048, 256, 0, stream>>>(xf, WxhT, b_h, xwp, 65536, 512, 512);

  // sequential scan: 4 self-contained WGs, all W on-CU (regs+LDS)
  k_scan_w4<<<4, 256, 0, stream>>>(xwp, Wf, xf /*hs*/, out + XWN);

  // logits = hs @ W_o + b_o   (f32 out)
  k_gemm<0><<<2048, 256, 0, stream>>>(xf, WoT, b_o, out, 65536, 512, 512);
}

// Round 10
// 2764.534 us; speedup vs baseline: 1.1438x; 1.1438x over previous
//
#include <hip/hip_runtime.h>

typedef _Float16 f16;
typedef __attribute__((ext_vector_type(4))) _Float16 f16x4;
typedef __attribute__((ext_vector_type(8))) _Float16 f16x8;
typedef __attribute__((ext_vector_type(4))) float f32x4;

__device__ __forceinline__ float tanh_fast(float x) {
  float e = __expf(2.0f * x);
  return 1.0f - 2.0f * __builtin_amdgcn_rcpf(e + 1.0f);
}

// raw LDS-only workgroup sync: no vmcnt drain (keeps global prefetches alive)
__device__ __forceinline__ void wg_sync_lds() {
  asm volatile("s_waitcnt lgkmcnt(0)" ::: "memory");
  __builtin_amdgcn_sched_barrier(0);
  __builtin_amdgcn_s_barrier();
  __builtin_amdgcn_sched_barrier(0);
}

#if defined(__has_builtin)
#if __has_builtin(__builtin_amdgcn_global_load_lds)
#define USE_GLL 1
#endif
#endif
#ifndef USE_GLL
#define USE_GLL 0
#endif

__device__ __forceinline__ void gll16(const void* g, void* l) {
#if USE_GLL
  __builtin_amdgcn_global_load_lds(
      (const __attribute__((address_space(1))) unsigned int*)g,
      (__attribute__((address_space(3))) unsigned int*)l, 16, 0, 0);
#endif
}

// ---------------- fp32 -> fp16 convert (grid-stride, float4) ----------------
__global__ void k_cvt_f16(const float* __restrict__ in, f16* __restrict__ out, int n4) {
  int i = blockIdx.x * blockDim.x + threadIdx.x;
  int stride = gridDim.x * blockDim.x;
  for (; i < n4; i += stride) {
    float4 v = reinterpret_cast<const float4*>(in)[i];
    f16x4 o;
    o[0] = (f16)v.x; o[1] = (f16)v.y; o[2] = (f16)v.z; o[3] = (f16)v.w;
    *reinterpret_cast<f16x4*>(out + (size_t)i * 4) = o;
  }
}

// ------------- 512x512 transpose + convert: out[n][k] = f16(in[k][n]) -------
__global__ __launch_bounds__(256) void k_transpose_cvt(const float* __restrict__ in,
                                                       f16* __restrict__ out) {
  __shared__ float tile[32][33];
  int bx = blockIdx.x & 15, by = blockIdx.x >> 4;
  int tx = threadIdx.x & 31, ty = threadIdx.x >> 5;
#pragma unroll
  for (int i = 0; i < 4; ++i)
    tile[ty + i * 8][tx] = in[(size_t)(by * 32 + ty + i * 8) * 512 + bx * 32 + tx];
  __syncthreads();
#pragma unroll
  for (int i = 0; i < 4; ++i)
    out[(size_t)(bx * 32 + ty + i * 8) * 512 + by * 32 + tx] = (f16)tile[tx][ty + i * 8];
}

// --------- W_hh frag-pack: Wf[cb][kt][q][c][e] = f16(W_hh[kt*32+q*8+e][cb*16+c])
__global__ __launch_bounds__(256) void k_packW(const float* __restrict__ Whh,
                                               f16* __restrict__ Wf) {
  int id = blockIdx.x * 256 + threadIdx.x;
  int c = id & 15, q = (id >> 4) & 3, kt = (id >> 6) & 15, cb = id >> 10;
  f16x8 blk;
#pragma unroll
  for (int e = 0; e < 8; ++e)
    blk[e] = (f16)Whh[(size_t)(kt * 32 + q * 8 + e) * 512 + cb * 16 + c];
  reinterpret_cast<f16x8*>(Wf)[id] = blk;
}

// ---------------- fp16 MFMA GEMM: C[M][N] = A[M][K] * Bt[N][K]^T + bias -----
// OUT: 0 = f32 linear, 2 = f16 packed-xw (scan-ready layout, ts-major blocks)
#define BM 128
#define BN 128
#define BK 32

template <int OUT>
__global__ __launch_bounds__(256, 2) void k_gemm(const f16* __restrict__ A,
                                                 const f16* __restrict__ Bt,
                                                 const float* __restrict__ bias,
                                                 void* __restrict__ Cout,
                                                 int M, int N, int K) {
  __shared__ __align__(16) f16 As[2][BM][BK];
  __shared__ __align__(16) f16 Bs[2][BN][BK];

  const int tid = threadIdx.x;
  const int w = tid >> 6;
  const int l = tid & 63;
  const int nbn = N / BN;
  const int bm0 = (int)(blockIdx.x / nbn) * BM;
  const int bn0 = (int)(blockIdx.x % nbn) * BN;
  const int wm = w >> 1, wn = w & 1;

  auto stage = [&](int buf, int kt) {
#pragma unroll
    for (int c = 0; c < 2; ++c) {
      const int row = c * 64 + w * 16 + (l >> 2);
      const int ke = kt + (l & 3) * 8;
#if USE_GLL
      gll16(A + (size_t)(bm0 + row) * K + ke, &As[buf][c * 64 + w * 16][0]);
      gll16(Bt + (size_t)(bn0 + row) * K + ke, &Bs[buf][c * 64 + w * 16][0]);
#else
      *(f16x8*)&As[buf][row][(l & 3) * 8] = *(const f16x8*)(A + (size_t)(bm0 + row) * K + ke);
      *(f16x8*)&Bs[buf][row][(l & 3) * 8] = *(const f16x8*)(Bt + (size_t)(bn0 + row) * K + ke);
#endif
    }
  };

  f32x4 acc[4][4] = {};
  const int nkt = K / BK;
  stage(0, 0);
  int cur = 0;
  for (int kt = 0; kt < nkt; ++kt) {
    __syncthreads();
    if (kt + 1 < nkt) stage(cur ^ 1, (kt + 1) * BK);
    f16x8 af[4], bfr[4];
#pragma unroll
    for (int m = 0; m < 4; ++m)
      af[m] = *(const f16x8*)&As[cur][wm * 64 + m * 16 + (l & 15)][(l >> 4) * 8];
#pragma unroll
    for (int n = 0; n < 4; ++n)
      bfr[n] = *(const f16x8*)&Bs[cur][wn * 64 + n * 16 + (l & 15)][(l >> 4) * 8];
#pragma unroll
    for (int m = 0; m < 4; ++m)
#pragma unroll
      for (int n = 0; n < 4; ++n)
        acc[m][n] = __builtin_amdgcn_mfma_f32_16x16x32_f16(af[m], bfr[n], acc[m][n], 0, 0, 0);
    cur ^= 1;
  }

  // Epilogue. C/D layout: col = lane&15, row = (lane>>4)*4 + j  [HW-verified]
  const int r0 = bm0 + wm * 64, c0 = bn0 + wn * 64;
#pragma unroll
  for (int n = 0; n < 4; ++n) {
    const int cc = c0 + n * 16 + (l & 15);
    const float bv = bias[cc];
#pragma unroll
    for (int m = 0; m < 4; ++m) {
      const int rr = r0 + m * 16 + ((l >> 4) << 2);
      if (OUT == 2) {
        // packed xw element (b,t,cc): idx =
        //  (((((set*256+tq)*8+ww)*4+qq)*4+jj)*16+c2)*16 + ts*4 + ii;  (GEMM j == ts)
        const int b = rr >> 10, trow = rr & 1023;
        const int set = b >> 4, qq = (b >> 2) & 3, jj = b & 3;
        const int ww = (cc >> 4) & 7, ii = cc >> 7, c2 = cc & 15;
        const int tq = trow >> 2;
        f16* po = (f16*)Cout +
                  ((((((size_t)set * 256 + tq) * 8 + ww) * 4 + qq) * 4 + jj) * 16 + c2) * 16 + ii;
#pragma unroll
        for (int j = 0; j < 4; ++j) po[j * 4] = (f16)(acc[m][n][j] + bv);
      } else {
#pragma unroll
        for (int j = 0; j < 4; ++j)
          ((float*)Cout)[(size_t)(rr + j) * N + cc] = acc[m][n][j] + bv;
      }
    }
  }
}

// ---------------- RNN scan: 4 waves/CU, 6 cb in regs (2 VGPR + 4 AGPR) ------
// 4 WGs x 256 threads (4 waves, 1/SIMD, 512-reg unified class). Wave w owns
// cbs {w+4i, i=0..5}: wr[0..1] in VGPRs (128v), wr[2..5] PINNED to AGPRs
// (256a) via inline-asm "+a" — MFMA reads B directly from AGPR (ISA §10),
// and asm volatile is non-rematerializable, so the compiler cannot re-load
// W from L2 per step (r9's failure: VGPR_Count=240 < 384 proved remat).
// cbs {24+w, 28+w} from LDS (128 KiB). h single-buffered [16][536] f16.
#define SCAN_T 1024

__global__ __launch_bounds__(256, 1) void k_scan_w4(
    const f16* __restrict__ xwp,   // packed xw (see k_gemm OUT==2)
    const f16* __restrict__ Wf,    // frag-packed [32][16][4][16][8]
    f16* __restrict__ hs,          // [64][1024][512] linear f16 (out)
    float* __restrict__ h_last) {  // [64][512] f32 (out)
  const int tid = threadIdx.x;
  const int w = tid >> 6, l = tid & 63;
  const int q = l >> 4, c = l & 15;
  const int set = blockIdx.x;
  const int b0 = set * 16;

  __shared__ __align__(16) f16 wlds[8 * 16 * 4 * 16 * 8];  // 128 KiB: cb 24..31
  __shared__ __align__(16) f16 h3[16 * 536];               // 16.75 KiB
  char* const h3b = (char*)h3;
  char* const wldsb = (char*)wlds;

  const f16x8* WfB = (const f16x8*)Wf;

  // register-resident W: cb w+4i, i=0..5  (384 regs = 128 VGPR + 256 AGPR)
  f16x8 wr[6][16];
#pragma unroll
  for (int i2 = 0; i2 < 6; ++i2)
#pragma unroll
    for (int kt = 0; kt < 16; ++kt)
      wr[i2][kt] = WfB[(((w + 4 * i2) * 16 + kt) * 4 + q) * 16 + c];

  // pin cb groups 2..5 into AGPRs (exactly 256 a-regs). MFMA consumes the
  // B operand from AGPR directly; no per-use copy expected.
#pragma unroll
  for (int i2 = 2; i2 < 6; ++i2)
#pragma unroll
    for (int kt = 0; kt < 16; ++kt)
      asm volatile("" : "+a"(wr[i2][kt]));

  // stage cb 24..31 into wlds (32 KiB per wave, async, linear)
#pragma unroll
  for (int k2 = 0; k2 < 32; ++k2) {
    gll16(WfB + 24 * 1024 + (w * 32 + k2) * 64 + l, wldsb + (size_t)(w * 32 + k2) * 1024);
#if !USE_GLL
    ((f16x8*)wldsb)[(w * 32 + k2) * 64 + l] = WfB[24 * 1024 + (w * 32 + k2) * 64 + l];
#endif
  }
  // zero h3 (h0 = 0)
  {
    uint4* hz = (uint4*)h3b;
    for (int i = tid; i < 1072; i += 256) hz[i] = make_uint4(0u, 0u, 0u, 0u);
  }

  // addressing (r6-verified frag map, stride 1072)
  const int afbase = c * 1072 + ((q ^ (c >> 2)) << 4);   // + kt*64
  const int wlb0 = w * 16384 + q * 256 + c * 16;          // + kt*1024 (cb 24+w)
  const int wlb1 = (4 + w) * 16384 + q * 256 + c * 16;    // + kt*1024 (cb 28+w)
  int woff8[8];
#pragma unroll
  for (int i2 = 0; i2 < 8; ++i2)
    woff8[i2] = q * 4 * 1072 + ((((w + 4 * i2) * 16 + c) ^ (q << 3)) << 1);  // + j*1072

  // hs bases per j (element ptr incl. lane col offset); col += i2*64 elems
  f16* hsb[4];
#pragma unroll
  for (int j = 0; j < 4; ++j)
    hsb[j] = hs + (size_t)(b0 + q * 4 + j) * SCAN_T * 512 + w * 16 + c;

  // packed-xw lane base; per (tq,ts,h,j): + tq*32768 + h*16384 + j*256 + ts*4
  const f16* xwbase =
      xwp + ((((size_t)set * 256 * 8 + w) * 4 + q) * 4) * 256 + c * 16;

  // prologue: xv = step-0 values  (xv[j][h][ii], h selects ww = w + 4h)
  f16x4 xv[4][2];
#pragma unroll
  for (int j = 0; j < 4; ++j) {
    xv[j][0] = __builtin_nontemporal_load((const f16x4*)(xwbase + j * 256));
    xv[j][1] = __builtin_nontemporal_load((const f16x4*)(xwbase + 16384 + j * 256));
  }

  __syncthreads();  // staging + zero complete (drains gll vmcnt too)

  for (int tq = 0; tq < 256; ++tq) {
#pragma unroll
    for (int ts = 0; ts < 4; ++ts) {
      const int t = tq * 4 + ts;

      // acc init from xw (C-in of the chains)
      f32x4 acc[8];
#pragma unroll
      for (int i2 = 0; i2 < 8; ++i2)
#pragma unroll
        for (int j = 0; j < 4; ++j)
          acc[i2][j] = (float)xv[j][i2 & 1][i2 >> 1];

      // reload xv for t+1 (in flight during MFMA+tail, consumed next step)
      {
        const int tqn = (ts == 3) ? ((tq < 255) ? tq + 1 : 255) : tq;
        const int tsn = (ts + 1) & 3;
        const f16* pb = xwbase + (size_t)tqn * 32768 + tsn * 4;
#pragma unroll
        for (int j = 0; j < 4; ++j) {
          xv[j][0] = __builtin_nontemporal_load((const f16x4*)(pb + j * 256));
          xv[j][1] = __builtin_nontemporal_load((const f16x4*)(pb + 16384 + j * 256));
        }
      }

      // MFMA: 8 chains (6 reg-W, 2 LDS-W), h from LDS
#pragma unroll
      for (int kt = 0; kt < 16; ++kt) {
        f16x8 af = *(const f16x8*)(h3b + afbase + kt * 64);
        f16x8 wl0 = *(const f16x8*)(wldsb + wlb0 + kt * 1024);
        f16x8 wl1 = *(const f16x8*)(wldsb + wlb1 + kt * 1024);
        acc[0] = __builtin_amdgcn_mfma_f32_16x16x32_f16(af, wr[0][kt], acc[0], 0, 0, 0);
        acc[1] = __builtin_amdgcn_mfma_f32_16x16x32_f16(af, wr[1][kt], acc[1], 0, 0, 0);
        acc[2] = __builtin_amdgcn_mfma_f32_16x16x32_f16(af, wr[2][kt], acc[2], 0, 0, 0);
        acc[3] = __builtin_amdgcn_mfma_f32_16x16x32_f16(af, wr[3][kt], acc[3], 0, 0, 0);
        acc[4] = __builtin_amdgcn_mfma_f32_16x16x32_f16(af, wr[4][kt], acc[4], 0, 0, 0);
        acc[5] = __builtin_amdgcn_mfma_f32_16x16x32_f16(af, wr[5][kt], acc[5], 0, 0, 0);
        acc[6] = __builtin_amdgcn_mfma_f32_16x16x32_f16(af, wl0, acc[6], 0, 0, 0);
        acc[7] = __builtin_amdgcn_mfma_f32_16x16x32_f16(af, wl1, acc[7], 0, 0, 0);
      }
      wg_sync_lds();  // B1: all h3 reads of h(t) complete

      // tail: tanh + h3 write + direct hs store
#pragma unroll
      for (int i2 = 0; i2 < 8; ++i2)
#pragma unroll
        for (int j = 0; j < 4; ++j) {
          float hv = tanh_fast(acc[i2][j]);
          *(f16*)(h3b + woff8[i2] + j * 1072) = (f16)hv;
          __builtin_nontemporal_store((f16)hv, hsb[j] + (size_t)t * 512 + i2 * 64);
        }
      wg_sync_lds();  // B2: h(t+1) visible
    }
  }

  // epilogue: h_last (f32) from h3 = h(1024)
  {
    const int m = tid >> 4, kt = tid & 15;
    float* hl = h_last + (size_t)(b0 + m) * 512 + kt * 32;
#pragma unroll
    for (int kb = 0; kb < 4; ++kb) {
      f16x8 v = *(const f16x8*)(h3b + m * 1072 + kt * 64 + (((kb ^ (m >> 2)) & 3) << 4));
      float4 lo, hi;
      lo.x = (float)v[0]; lo.y = (float)v[1]; lo.z = (float)v[2]; lo.w = (float)v[3];
      hi.x = (float)v[4]; hi.y = (float)v[5]; hi.z = (float)v[6]; hi.w = (float)v[7];
      *(float4*)(hl + kb * 8) = lo;
      *(float4*)(hl + kb * 8 + 4) = hi;
    }
  }
}

// ---------------------------------------------------------------------------
extern "C" void kernel_launch(void* const* d_in, const int* in_sizes, int n_in,
                              void* d_out, int out_size, void* d_ws, size_t ws_size,
                              hipStream_t stream) {
  const float* x    = (const float*)d_in[0];
  const float* W_xh = (const float*)d_in[1];
  const float* b_h  = (const float*)d_in[2];
  const float* W_hh = (const float*)d_in[3];
  const float* W_o  = (const float*)d_in[4];
  const float* b_o  = (const float*)d_in[5];
  float* out = (float*)d_out;  // logits [64][1024][512] ++ h_last [64][512]

  const size_t XWN = (size_t)64 * 1024 * 512;
  char* ws = (char*)d_ws;
  f16* xf   = (f16*)(ws);                       // 64 MiB (x f16 -> later hs)
  f16* xwp  = (f16*)(ws + XWN * 2);             // 64 MiB (packed xW f16)
  f16* WxhT = (f16*)(ws + XWN * 4);             // 512 KiB
  f16* WoT  = (f16*)(ws + XWN * 4 + 524288);    // 512 KiB
  f16* Wf   = (f16*)(ws + XWN * 4 + 1048576);   // 512 KiB (frag-packed W_hh)

  k_cvt_f16<<<4096, 256, 0, stream>>>(x, xf, (int)(XWN / 4));
  k_transpose_cvt<<<256, 256, 0, stream>>>(W_xh, WxhT);
  k_transpose_cvt<<<256, 256, 0, stream>>>(W_o, WoT);
  k_packW<<<128, 256, 0, stream>>>(W_hh, Wf);

  // xW = x @ W_xh + b_h, written in scan-packed (ts-major) layout
  k_gemm<2><<<2048, 256, 0, stream>>>(xf, WxhT, b_h, xwp, 65536, 512, 512);

  // sequential scan: 4 self-contained WGs, all W on-CU (VGPR+AGPR+LDS)
  k_scan_w4<<<4, 256, 0, stream>>>(xwp, Wf, xf /*hs*/, out + XWN);

  // logits = hs @ W_o + b_o   (f32 out)
  k_gemm<0><<<2048, 256, 0, stream>>>(xf, WoT, b_o, out, 65536, 512, 512);
}

// Round 12
// 2381.066 us; speedup vs baseline: 1.3280x; 1.1610x over previous
//
#include <hip/hip_runtime.h>

typedef _Float16 f16;
typedef __attribute__((ext_vector_type(4))) _Float16 f16x4;
typedef __attribute__((ext_vector_type(8))) _Float16 f16x8;
typedef __attribute__((ext_vector_type(4))) float f32x4;

__device__ __forceinline__ float tanh_fast(float x) {
  float e = __expf(2.0f * x);
  return 1.0f - 2.0f * __builtin_amdgcn_rcpf(e + 1.0f);
}

// raw LDS-only workgroup sync: no vmcnt drain (keeps global prefetches alive)
__device__ __forceinline__ void wg_sync_lds() {
  asm volatile("s_waitcnt lgkmcnt(0)" ::: "memory");
  __builtin_amdgcn_sched_barrier(0);
  __builtin_amdgcn_s_barrier();
  __builtin_amdgcn_sched_barrier(0);
}

#if defined(__has_builtin)
#if __has_builtin(__builtin_amdgcn_global_load_lds)
#define USE_GLL 1
#endif
#endif
#ifndef USE_GLL
#define USE_GLL 0
#endif

__device__ __forceinline__ void gll16(const void* g, void* l) {
#if USE_GLL
  __builtin_amdgcn_global_load_lds(
      (const __attribute__((address_space(1))) unsigned int*)g,
      (__attribute__((address_space(3))) unsigned int*)l, 16, 0, 0);
#endif
}

// ---------------- fp32 -> fp16 convert (grid-stride, float4) ----------------
__global__ void k_cvt_f16(const float* __restrict__ in, f16* __restrict__ out, int n4) {
  int i = blockIdx.x * blockDim.x + threadIdx.x;
  int stride = gridDim.x * blockDim.x;
  for (; i < n4; i += stride) {
    float4 v = reinterpret_cast<const float4*>(in)[i];
    f16x4 o;
    o[0] = (f16)v.x; o[1] = (f16)v.y; o[2] = (f16)v.z; o[3] = (f16)v.w;
    *reinterpret_cast<f16x4*>(out + (size_t)i * 4) = o;
  }
}

// ------------- 512x512 transpose + convert: out[n][k] = f16(in[k][n]) -------
__global__ __launch_bounds__(256) void k_transpose_cvt(const float* __restrict__ in,
                                                       f16* __restrict__ out) {
  __shared__ float tile[32][33];
  int bx = blockIdx.x & 15, by = blockIdx.x >> 4;
  int tx = threadIdx.x & 31, ty = threadIdx.x >> 5;
#pragma unroll
  for (int i = 0; i < 4; ++i)
    tile[ty + i * 8][tx] = in[(size_t)(by * 32 + ty + i * 8) * 512 + bx * 32 + tx];
  __syncthreads();
#pragma unroll
  for (int i = 0; i < 4; ++i)
    out[(size_t)(bx * 32 + ty + i * 8) * 512 + by * 32 + tx] = (f16)tile[tx][ty + i * 8];
}

// --------- W_hh frag-pack: Wf[cb][kt][q][c][e] = f16(W_hh[kt*32+q*8+e][cb*16+c])
__global__ __launch_bounds__(256) void k_packW(const float* __restrict__ Whh,
                                               f16* __restrict__ Wf) {
  int id = blockIdx.x * 256 + threadIdx.x;
  int c = id & 15, q = (id >> 4) & 3, kt = (id >> 6) & 15, cb = id >> 10;
  f16x8 blk;
#pragma unroll
  for (int e = 0; e < 8; ++e)
    blk[e] = (f16)Whh[(size_t)(kt * 32 + q * 8 + e) * 512 + cb * 16 + c];
  reinterpret_cast<f16x8*>(Wf)[id] = blk;
}

// ---------------- fp16 MFMA GEMM: C[M][N] = A[M][K] * Bt[N][K]^T + bias -----
// OUT: 0 = f32 linear, 2 = f16 packed-xw (scan-ready layout, ts-major blocks)
#define BM 128
#define BN 128
#define BK 32

template <int OUT>
__global__ __launch_bounds__(256, 2) void k_gemm(const f16* __restrict__ A,
                                                 const f16* __restrict__ Bt,
                                                 const float* __restrict__ bias,
                                                 void* __restrict__ Cout,
                                                 int M, int N, int K) {
  __shared__ __align__(16) f16 As[2][BM][BK];
  __shared__ __align__(16) f16 Bs[2][BN][BK];

  const int tid = threadIdx.x;
  const int w = tid >> 6;
  const int l = tid & 63;
  const int nbn = N / BN;
  const int bm0 = (int)(blockIdx.x / nbn) * BM;
  const int bn0 = (int)(blockIdx.x % nbn) * BN;
  const int wm = w >> 1, wn = w & 1;

  auto stage = [&](int buf, int kt) {
#pragma unroll
    for (int c = 0; c < 2; ++c) {
      const int row = c * 64 + w * 16 + (l >> 2);
      const int ke = kt + (l & 3) * 8;
#if USE_GLL
      gll16(A + (size_t)(bm0 + row) * K + ke, &As[buf][c * 64 + w * 16][0]);
      gll16(Bt + (size_t)(bn0 + row) * K + ke, &Bs[buf][c * 64 + w * 16][0]);
#else
      *(f16x8*)&As[buf][row][(l & 3) * 8] = *(const f16x8*)(A + (size_t)(bm0 + row) * K + ke);
      *(f16x8*)&Bs[buf][row][(l & 3) * 8] = *(const f16x8*)(Bt + (size_t)(bn0 + row) * K + ke);
#endif
    }
  };

  f32x4 acc[4][4] = {};
  const int nkt = K / BK;
  stage(0, 0);
  int cur = 0;
  for (int kt = 0; kt < nkt; ++kt) {
    __syncthreads();
    if (kt + 1 < nkt) stage(cur ^ 1, (kt + 1) * BK);
    f16x8 af[4], bfr[4];
#pragma unroll
    for (int m = 0; m < 4; ++m)
      af[m] = *(const f16x8*)&As[cur][wm * 64 + m * 16 + (l & 15)][(l >> 4) * 8];
#pragma unroll
    for (int n = 0; n < 4; ++n)
      bfr[n] = *(const f16x8*)&Bs[cur][wn * 64 + n * 16 + (l & 15)][(l >> 4) * 8];
#pragma unroll
    for (int m = 0; m < 4; ++m)
#pragma unroll
      for (int n = 0; n < 4; ++n)
        acc[m][n] = __builtin_amdgcn_mfma_f32_16x16x32_f16(af[m], bfr[n], acc[m][n], 0, 0, 0);
    cur ^= 1;
  }

  // Epilogue. C/D layout: col = lane&15, row = (lane>>4)*4 + j  [HW-verified]
  const int r0 = bm0 + wm * 64, c0 = bn0 + wn * 64;
#pragma unroll
  for (int n = 0; n < 4; ++n) {
    const int cc = c0 + n * 16 + (l & 15);
    const float bv = bias[cc];
#pragma unroll
    for (int m = 0; m < 4; ++m) {
      const int rr = r0 + m * 16 + ((l >> 4) << 2);
      if (OUT == 2) {
        // packed xw element (b,t,cc): idx =
        //  (((((set*256+tq)*8+ww)*4+qq)*4+jj)*16+c2)*16 + ts*4 + ii;  (GEMM j == ts)
        const int b = rr >> 10, trow = rr & 1023;
        const int set = b >> 4, qq = (b >> 2) & 3, jj = b & 3;
        const int ww = (cc >> 4) & 7, ii = cc >> 7, c2 = cc & 15;
        const int tq = trow >> 2;
        f16* po = (f16*)Cout +
                  ((((((size_t)set * 256 + tq) * 8 + ww) * 4 + qq) * 4 + jj) * 16 + c2) * 16 + ii;
#pragma unroll
        for (int j = 0; j < 4; ++j) po[j * 4] = (f16)(acc[m][n][j] + bv);
      } else {
#pragma unroll
        for (int j = 0; j < 4; ++j)
          ((float*)Cout)[(size_t)(rr + j) * N + cc] = acc[m][n][j] + bv;
      }
    }
  }
}

// ---------------- RNN scan: 8 waves (2/SIMD TLP) + W pinned in regs ---------
// 4 WGs x 512 threads. Wave w owns cb {w, 8+w, 16+w} register-resident and
// PINNED (wb0 -> 64 VGPR via "+v"; wb1/wb2 -> 128 AGPR via "+a"; asm is
// non-rematerializable so the compiler cannot re-load W from L2 per step —
// r6's hidden failure: VGPR_Count=128 < 192 proved remat). cb {24+w} from
// LDS (128 KiB). h single-buffered [16][536] f16 (stride 1072), r9-verified
// maps. Direct hs stores; h_last epilogue. 2 LDS-only barriers/step.
#define SCAN_T 1024

__global__ __launch_bounds__(512, 2) void k_scan_w8(
    const f16* __restrict__ xwp,   // packed xw (see k_gemm OUT==2)
    const f16* __restrict__ Wf,    // frag-packed [32][16][4][16][8]
    f16* __restrict__ hs,          // [64][1024][512] linear f16 (out)
    float* __restrict__ h_last) {  // [64][512] f32 (out)
  const int tid = threadIdx.x;
  const int w = tid >> 6, l = tid & 63;
  const int q = l >> 4, c = l & 15;
  const int set = blockIdx.x;
  const int b0 = set * 16;

  __shared__ __align__(16) f16 wlds[8 * 16 * 64 * 8];  // 128 KiB: cb 24..31
  __shared__ __align__(16) f16 h3[16 * 536];           // 16.75 KiB
  char* const h3b = (char*)h3;
  char* const wldsb = (char*)wlds;

  const f16x8* WfB = (const f16x8*)Wf;

  // register-resident W: cb w, 8+w, 16+w  (192 regs: 64 VGPR + 128 AGPR)
  f16x8 wb0[16], wb1[16], wb2[16];
#pragma unroll
  for (int kt = 0; kt < 16; ++kt) {
    wb0[kt] = WfB[((w * 16 + kt) * 4 + q) * 16 + c];
    wb1[kt] = WfB[(((8 + w) * 16 + kt) * 4 + q) * 16 + c];
    wb2[kt] = WfB[(((16 + w) * 16 + kt) * 4 + q) * 16 + c];
  }
  // pin: wb0 stays VGPR; wb1/wb2 to AGPR. Non-remat (asm volatile producer).
#pragma unroll
  for (int kt = 0; kt < 16; ++kt) {
    asm volatile("" : "+v"(wb0[kt]));
    asm volatile("" : "+a"(wb1[kt]));
    asm volatile("" : "+a"(wb2[kt]));
  }

  // stage cb 24..31 into wlds (16 KiB per wave, async, linear)
#pragma unroll
  for (int k2 = 0; k2 < 16; ++k2) {
    gll16(WfB + ((24 + w) * 16 + k2) * 64 + l, wldsb + (size_t)(w * 16 + k2) * 1024);
#if !USE_GLL
    ((f16x8*)wldsb)[(w * 16 + k2) * 64 + l] = WfB[((24 + w) * 16 + k2) * 64 + l];
#endif
  }
  // zero h3 (h0 = 0)
  {
    uint4* hz = (uint4*)h3b;
    for (int i = tid; i < 1072; i += 512) hz[i] = make_uint4(0u, 0u, 0u, 0u);
  }

  // addressing (r9-verified frag map, stride 1072)
  const int afbase = c * 1072 + ((q ^ (c >> 2)) << 4);  // + kt*64
  const int wlb = w * 16384 + q * 256 + c * 16;         // + kt*1024 (cb 24+w)
  const int cbs[4] = {w, 8 + w, 16 + w, 24 + w};
  int woff[4];
#pragma unroll
  for (int i2 = 0; i2 < 4; ++i2)
    woff[i2] = q * 4 * 1072 + (((cbs[i2] * 16 + c) ^ (q << 3)) << 1);  // + j*1072

  // hs bases per j; store offset = t*512 + i2*128 elems (cbs[i2]*16 = w*16+i2*128)
  f16* hsb[4];
#pragma unroll
  for (int j = 0; j < 4; ++j)
    hsb[j] = hs + (size_t)(b0 + q * 4 + j) * SCAN_T * 512 + w * 16 + c;

  // packed-xw lane base; per (tq,ts,j): + tq*32768 + j*256 + ts*4; elem ii=i2
  const f16* xwbase =
      xwp + ((((size_t)set * 256 * 8 + w) * 4 + q) * 4) * 256 + c * 16;

  // prologue: xv = step-0 values (single buffer; reloaded after consumption)
  f16x4 xv[4];
#pragma unroll
  for (int j = 0; j < 4; ++j)
    xv[j] = __builtin_nontemporal_load((const f16x4*)(xwbase + j * 256));

  __syncthreads();  // staging + zero complete (drains gll vmcnt too)

  for (int tq = 0; tq < 256; ++tq) {
#pragma unroll
    for (int ts = 0; ts < 4; ++ts) {
      const int t = tq * 4 + ts;

      // acc init from xw (C-in of the chains)
      f32x4 acc[4];
#pragma unroll
      for (int i2 = 0; i2 < 4; ++i2)
#pragma unroll
        for (int j = 0; j < 4; ++j) acc[i2][j] = (float)xv[j][i2];

      // reload xv for t+1 (lands during MFMA+tail; consumed next step)
      {
        const int tqn = (ts == 3) ? ((tq < 255) ? tq + 1 : 255) : tq;
        const int tsn = (ts + 1) & 3;
        const f16* pb = xwbase + (size_t)tqn * 32768 + tsn * 4;
#pragma unroll
        for (int j = 0; j < 4; ++j)
          xv[j] = __builtin_nontemporal_load((const f16x4*)(pb + j * 256));
      }

      // MFMA: 4 chains (3 pinned-reg W, 1 LDS-W), h from LDS
#pragma unroll
      for (int kt = 0; kt < 16; ++kt) {
        f16x8 af = *(const f16x8*)(h3b + afbase + kt * 64);
        f16x8 wl = *(const f16x8*)(wldsb + wlb + kt * 1024);
        acc[0] = __builtin_amdgcn_mfma_f32_16x16x32_f16(af, wb0[kt], acc[0], 0, 0, 0);
        acc[1] = __builtin_amdgcn_mfma_f32_16x16x32_f16(af, wb1[kt], acc[1], 0, 0, 0);
        acc[2] = __builtin_amdgcn_mfma_f32_16x16x32_f16(af, wb2[kt], acc[2], 0, 0, 0);
        acc[3] = __builtin_amdgcn_mfma_f32_16x16x32_f16(af, wl, acc[3], 0, 0, 0);
      }
      wg_sync_lds();  // B1: all h3 reads of h(t) complete

      // tail: tanh + h3 write + direct hs store
#pragma unroll
      for (int i2 = 0; i2 < 4; ++i2)
#pragma unroll
        for (int j = 0; j < 4; ++j) {
          float hv = tanh_fast(acc[i2][j]);
          *(f16*)(h3b + woff[i2] + j * 1072) = (f16)hv;
          __builtin_nontemporal_store((f16)hv, hsb[j] + (size_t)t * 512 + i2 * 128);
        }
      wg_sync_lds();  // B2: h(t+1) visible
    }
  }

  // epilogue: h_last (f32) from h3 = h(1024)
  if (tid < 256) {
    const int m = tid >> 4, kt = tid & 15;
    float* hl = h_last + (size_t)(b0 + m) * 512 + kt * 32;
#pragma unroll
    for (int kb = 0; kb < 4; ++kb) {
      f16x8 v = *(const f16x8*)(h3b + m * 1072 + kt * 64 + (((kb ^ (m >> 2)) & 3) << 4));
      float4 lo, hi;
      lo.x = (float)v[0]; lo.y = (float)v[1]; lo.z = (float)v[2]; lo.w = (float)v[3];
      hi.x = (float)v[4]; hi.y = (float)v[5]; hi.z = (float)v[6]; hi.w = (float)v[7];
      *(float4*)(hl + kb * 8) = lo;
      *(float4*)(hl + kb * 8 + 4) = hi;
    }
  }
}

// ---------------------------------------------------------------------------
extern "C" void kernel_launch(void* const* d_in, const int* in_sizes, int n_in,
                              void* d_out, int out_size, void* d_ws, size_t ws_size,
                              hipStream_t stream) {
  const float* x    = (const float*)d_in[0];
  const float* W_xh = (const float*)d_in[1];
  const float* b_h  = (const float*)d_in[2];
  const float* W_hh = (const float*)d_in[3];
  const float* W_o  = (const float*)d_in[4];
  const float* b_o  = (const float*)d_in[5];
  float* out = (float*)d_out;  // logits [64][1024][512] ++ h_last [64][512]

  const size_t XWN = (size_t)64 * 1024 * 512;
  char* ws = (char*)d_ws;
  f16* xf   = (f16*)(ws);                       // 64 MiB (x f16 -> later hs)
  f16* xwp  = (f16*)(ws + XWN * 2);             // 64 MiB (packed xW f16)
  f16* WxhT = (f16*)(ws + XWN * 4);             // 512 KiB
  f16* WoT  = (f16*)(ws + XWN * 4 + 524288);    // 512 KiB
  f16* Wf   = (f16*)(ws + XWN * 4 + 1048576);   // 512 KiB (frag-packed W_hh)

  k_cvt_f16<<<4096, 256, 0, stream>>>(x, xf, (int)(XWN / 4));
  k_transpose_cvt<<<256, 256, 0, stream>>>(W_xh, WxhT);
  k_transpose_cvt<<<256, 256, 0, stream>>>(W_o, WoT);
  k_packW<<<128, 256, 0, stream>>>(W_hh, Wf);

  // xW = x @ W_xh + b_h, written in scan-packed (ts-major) layout
  k_gemm<2><<<2048, 256, 0, stream>>>(xf, WxhT, b_h, xwp, 65536, 512, 512);

  // sequential scan: 4 self-contained WGs, 8 waves, W pinned on-CU
  k_scan_w8<<<4, 512, 0, stream>>>(xwp, Wf, xf /*hs*/, out + XWN);

  // logits = hs @ W_o + b_o   (f32 out)
  k_gemm<0><<<2048, 256, 0, stream>>>(xf, WoT, b_o, out, 65536, 512, 512);
}